// Round 1
// baseline (723.580 us; speedup 1.0000x reference)
//
#include <hip/hip_runtime.h>
#include <math.h>

// PaiNN QM encoder, fp32, algebraically refactored:
//   U = V_JK @ W1b   (N,3,256)     T = b1 + n_i@W1c + S_JK@W1d   (N,256)
//   per edge: m1 = T[i] + e_pi@W1a + r_hat . U[i]  -> silu -> @W2 -> silu -> @w3 -> *cw -> scatter
// ws layout (floats): [region1: VJK | SJK | NI  (reused later as EPI|RCW)] [U] [T]

#define L_DIM 6
#define F_DIM 256
#define FH_DIM 128
#define DRBF 32
#define CUTOFF_F 4.0f
#define PI_F 3.14159265358979323846f

__device__ __forceinline__ float silu_f(float x){ return x / (1.f + __expf(-x)); }

// ---------------- Kernel A1: attention + S_JK / V_JK / n_i ----------------
// 8 atoms per block, 256 threads. j = t&127 owns one FH column; lgu = t>>7 picks l-half.
__global__ __launch_bounds__(256) void kA1(
    const float* __restrict__ s_stack, const float* __restrict__ v_stack,
    const float* __restrict__ attn_w1, const float* __restrict__ attn_b1,
    const float* __restrict__ attn_w2, const float* __restrict__ attn_b2,
    float* __restrict__ VJK, float* __restrict__ SJK, float* __restrict__ NI,
    int N)
{
    __shared__ float red[4][8][3];
    __shared__ float alds[8][L_DIM];

    const int t = threadIdx.x;
    const int n0 = blockIdx.x * 8;
    const int j = t & (FH_DIM - 1);
    const int lgu  = __builtin_amdgcn_readfirstlane(t >> 7);  // 0..1 (wave-uniform)
    const int wave = __builtin_amdgcn_readfirstlane(t >> 6);  // 0..3

    // per-atom base pointers (uniform -> scalar loads for s values)
    const float* sb[8];
    #pragma unroll
    for (int a = 0; a < 8; a++){
        int n = n0 + a; if (n > N-1) n = N-1;
        sb[a] = s_stack + ((size_t)n * L_DIM + (size_t)lgu * 3) * F_DIM;
    }

    float hacc[8][3];
    #pragma unroll
    for (int a = 0; a < 8; a++){ hacc[a][0]=0.f; hacc[a][1]=0.f; hacc[a][2]=0.f; }

    #pragma unroll 4
    for (int f = 0; f < F_DIM; f++){
        float w = attn_w1[f * FH_DIM + j];           // per-lane column j, coalesced
        #pragma unroll
        for (int a = 0; a < 8; a++){
            hacc[a][0] = fmaf(sb[a][f],           w, hacc[a][0]);
            hacc[a][1] = fmaf(sb[a][F_DIM + f],   w, hacc[a][1]);
            hacc[a][2] = fmaf(sb[a][2*F_DIM + f], w, hacc[a][2]);
        }
    }

    const float b1j = attn_b1[j];
    const float w2j = attn_w2[j];
    const float b2s = attn_b2[0];

    #pragma unroll
    for (int a = 0; a < 8; a++){
        #pragma unroll
        for (int l3 = 0; l3 < 3; l3++){
            float pre = hacc[a][l3] + b1j;
            float p = silu_f(pre) * w2j;
            #pragma unroll
            for (int m = 32; m >= 1; m >>= 1) p += __shfl_xor(p, m, 64);
            if ((t & 63) == 0) red[wave][a][l3] = p;
        }
    }
    __syncthreads();
    if (t < 48){
        int a = t / L_DIM, l = t % L_DIM;
        int lg2 = l / 3, l3 = l % 3;
        alds[a][l] = red[lg2*2][a][l3] + red[lg2*2+1][a][l3] + b2s;
    }
    __syncthreads();
    if (t < 8){
        float mx = -1e30f;
        #pragma unroll
        for (int l = 0; l < L_DIM; l++) mx = fmaxf(mx, alds[t][l]);
        float e[L_DIM]; float s = 0.f;
        #pragma unroll
        for (int l = 0; l < L_DIM; l++){ e[l] = __expf(alds[t][l] - mx); s += e[l]; }
        float inv = 1.f / s;
        #pragma unroll
        for (int l = 0; l < L_DIM; l++) alds[t][l] = e[l] * inv;
    }
    __syncthreads();

    // weighted sums: thread t owns feature f=t, coalesced over f
    const int f = t;
    for (int a = 0; a < 8; a++){
        int n = n0 + a; if (n >= N) break;
        float aw[L_DIM];
        #pragma unroll
        for (int l = 0; l < L_DIM; l++) aw[l] = alds[a][l];
        const float* sp = s_stack + (size_t)n * L_DIM * F_DIM + f;
        float sjk = 0.f;
        #pragma unroll
        for (int l = 0; l < L_DIM; l++) sjk = fmaf(aw[l], sp[l * F_DIM], sjk);
        const float* vp = v_stack + (size_t)n * L_DIM * 3 * F_DIM + f;
        float v0 = 0.f, v1 = 0.f, v2 = 0.f;
        #pragma unroll
        for (int l = 0; l < L_DIM; l++){
            v0 = fmaf(aw[l], vp[(l*3+0)*F_DIM], v0);
            v1 = fmaf(aw[l], vp[(l*3+1)*F_DIM], v1);
            v2 = fmaf(aw[l], vp[(l*3+2)*F_DIM], v2);
        }
        SJK[(size_t)n * F_DIM + f] = sjk;
        VJK[((size_t)n*3 + 0) * F_DIM + f] = v0;
        VJK[((size_t)n*3 + 1) * F_DIM + f] = v1;
        VJK[((size_t)n*3 + 2) * F_DIM + f] = v2;
        NI[(size_t)n * F_DIM + f] = sqrtf(v0*v0 + v1*v1 + v2*v2);
    }
}

// ---------------- Kernel A2: U = VJK@W1b, T = b1 + NI@W1c + SJK@W1d ----------------
__global__ __launch_bounds__(256) void kA2(
    const float* __restrict__ msg_w1, const float* __restrict__ msg_b1,
    const float* __restrict__ VJK, const float* __restrict__ SJK, const float* __restrict__ NI,
    float* __restrict__ U, float* __restrict__ T, int N)
{
    const int t = threadIdx.x;            // output column j
    const int n0 = blockIdx.x * 8;

    float uacc[8][3];
    #pragma unroll
    for (int a = 0; a < 8; a++){ uacc[a][0]=0.f; uacc[a][1]=0.f; uacc[a][2]=0.f; }

    #pragma unroll 2
    for (int f = 0; f < F_DIM; f++){
        float w = msg_w1[(size_t)(DRBF + f) * F_DIM + t];     // W1b row f, coalesced
        #pragma unroll
        for (int a = 0; a < 8; a++){
            int n = n0 + a; if (n > N-1) n = N-1;
            const float* vb = VJK + (size_t)n * 3 * F_DIM + f;   // uniform -> scalar loads
            uacc[a][0] = fmaf(vb[0],         w, uacc[a][0]);
            uacc[a][1] = fmaf(vb[F_DIM],     w, uacc[a][1]);
            uacc[a][2] = fmaf(vb[2*F_DIM],   w, uacc[a][2]);
        }
    }
    #pragma unroll
    for (int a = 0; a < 8; a++){
        int n = n0 + a;
        if (n < N){
            U[((size_t)n*3 + 0)*F_DIM + t] = uacc[a][0];
            U[((size_t)n*3 + 1)*F_DIM + t] = uacc[a][1];
            U[((size_t)n*3 + 2)*F_DIM + t] = uacc[a][2];
        }
    }

    float tacc[8];
    const float b = msg_b1[t];
    #pragma unroll
    for (int a = 0; a < 8; a++) tacc[a] = b;

    #pragma unroll 2
    for (int f = 0; f < F_DIM; f++){
        float wc = msg_w1[(size_t)(DRBF + F_DIM   + f) * F_DIM + t];   // W1c (n_i)
        float wd = msg_w1[(size_t)(DRBF + 2*F_DIM + f) * F_DIM + t];   // W1d (S_JK)
        #pragma unroll
        for (int a = 0; a < 8; a++){
            int n = n0 + a; if (n > N-1) n = N-1;
            tacc[a] = fmaf(NI [(size_t)n*F_DIM + f], wc, tacc[a]);
            tacc[a] = fmaf(SJK[(size_t)n*F_DIM + f], wd, tacc[a]);
        }
    }
    #pragma unroll
    for (int a = 0; a < 8; a++){
        int n = n0 + a;
        if (n < N) T[(size_t)n*F_DIM + t] = tacc[a];
    }
}

// ---------------- Kernel B0: per-edge geometry -> EPI (E,32), RCW (E,4)=rhat,cw ----------------
__global__ __launch_bounds__(256) void kB0(
    const int* __restrict__ pe, const float* __restrict__ disp,
    const float* __restrict__ cell,
    const float* __restrict__ atom_xyz, const float* __restrict__ probe_xyz,
    float* __restrict__ EPI, float* __restrict__ RCW, int E)
{
    int e = blockIdx.x * 256 + threadIdx.x;
    if (e >= E) return;
    int i = pe[(size_t)e*2];
    int p = pe[(size_t)e*2 + 1];
    float d0 = disp[(size_t)e*3], d1 = disp[(size_t)e*3+1], d2 = disp[(size_t)e*3+2];
    float sx = d0*cell[0] + d1*cell[3] + d2*cell[6];
    float sy = d0*cell[1] + d1*cell[4] + d2*cell[7];
    float sz = d0*cell[2] + d1*cell[5] + d2*cell[8];
    float dx = probe_xyz[(size_t)p*3+0] - (atom_xyz[(size_t)i*3+0] + sx);
    float dy = probe_xyz[(size_t)p*3+1] - (atom_xyz[(size_t)i*3+1] + sy);
    float dz = probe_xyz[(size_t)p*3+2] - (atom_xyz[(size_t)i*3+2] + sz);
    float dist = sqrtf(dx*dx + dy*dy + dz*dz);
    float inv = 1.f / (dist + 1e-8f);
    RCW[(size_t)e*4+0] = dx * inv;
    RCW[(size_t)e*4+1] = dy * inv;
    RCW[(size_t)e*4+2] = dz * inv;
    RCW[(size_t)e*4+3] = (dist < CUTOFF_F) ? 0.5f * (cosf(PI_F * dist / CUTOFF_F) + 1.f) : 0.f;
    float base = dist * (PI_F / CUTOFF_F);
    #pragma unroll
    for (int k = 0; k < DRBF; k++)
        EPI[(size_t)e*DRBF + k] = sinf(base * (float)(k+1)) * inv;
}

// ---------------- Kernel B1: fused edge MLP + scatter ----------------
// 64 edges per block in two halves of 32. Layer1: thread t = column j (256).
// x stored transposed in LDS [k=256][e=32, pad 36]. Layer2: 2 edges x 8 h per thread.
__global__ __launch_bounds__(256) void kB1(
    const int* __restrict__ pe,
    const float* __restrict__ EPI, const float* __restrict__ RCW,
    const float* __restrict__ U, const float* __restrict__ T,
    const float* __restrict__ msg_w1,
    const float* __restrict__ msg_w2, const float* __restrict__ msg_b2,
    const float* __restrict__ msg_w3, const float* __restrict__ msg_b3,
    float* __restrict__ rho, int E)
{
    __shared__ float xT[F_DIM][36];   // [k][e], stride 36 -> conflict-free b64 reads

    const int t = threadIdx.x;
    const int e0 = blockIdx.x * 64;

    // layer-1: W1a column t in registers
    float w1a[DRBF];
    #pragma unroll
    for (int k = 0; k < DRBF; k++) w1a[k] = msg_w1[(size_t)k * F_DIM + t];

    // layer-2/3 mapping and constants
    const int hg = t & 15;
    const int eg = t >> 4;
    const int h0 = hg * 8;
    const int e2 = eg * 2;
    float w3r[8], b2r[8];
    #pragma unroll
    for (int hh = 0; hh < 8; hh++){ w3r[hh] = msg_w3[h0+hh]; b2r[hh] = msg_b2[h0+hh]; }
    const float b3 = msg_b3[0];

    for (int half = 0; half < 2; half++){
        if (half) __syncthreads();          // previous layer2 reads done before overwrite

        // ---- layer 1: x[e][t] for 32 edges ----
        #pragma unroll 2
        for (int e = 0; e < 32; e++){
            const int eec = min(e0 + half*32 + e, E-1);
            const int i = pe[(size_t)eec*2];                     // uniform -> SGPR
            const float rx = RCW[(size_t)eec*4+0];
            const float ry = RCW[(size_t)eec*4+1];
            const float rz = RCW[(size_t)eec*4+2];
            const float* Up = U + (size_t)i * (3*F_DIM);
            float acc = T[(size_t)i * F_DIM + t];
            float u0 = Up[t], u1 = Up[F_DIM + t], u2 = Up[2*F_DIM + t];
            const float* ep = EPI + (size_t)eec * DRBF;          // uniform -> scalar loads
            float p0=0.f, p1=0.f, p2=0.f, p3=0.f;
            #pragma unroll
            for (int k = 0; k < DRBF; k += 4){
                p0 = fmaf(ep[k+0], w1a[k+0], p0);
                p1 = fmaf(ep[k+1], w1a[k+1], p1);
                p2 = fmaf(ep[k+2], w1a[k+2], p2);
                p3 = fmaf(ep[k+3], w1a[k+3], p3);
            }
            acc += (p0 + p1) + (p2 + p3);
            acc = fmaf(rx, u0, fmaf(ry, u1, fmaf(rz, u2, acc)));
            xT[t][e] = silu_f(acc);
        }
        __syncthreads();

        // ---- layer 2 (256->128) + layer 3 (128->1) ----
        float acc2[2][8];
        #pragma unroll
        for (int hh = 0; hh < 8; hh++){ acc2[0][hh] = b2r[hh]; acc2[1][hh] = b2r[hh]; }

        #pragma unroll 2
        for (int k = 0; k < F_DIM; k++){
            float2 xv = *(const float2*)&xT[k][e2];
            const float4* wr = (const float4*)(msg_w2 + (size_t)k * FH_DIM + h0);
            float4 wa = wr[0], wb = wr[1];
            float wv[8] = {wa.x, wa.y, wa.z, wa.w, wb.x, wb.y, wb.z, wb.w};
            #pragma unroll
            for (int hh = 0; hh < 8; hh++){
                acc2[0][hh] = fmaf(xv.x, wv[hh], acc2[0][hh]);
                acc2[1][hh] = fmaf(xv.y, wv[hh], acc2[1][hh]);
            }
        }

        #pragma unroll
        for (int ei = 0; ei < 2; ei++){
            float msum = 0.f;
            #pragma unroll
            for (int hh = 0; hh < 8; hh++)
                msum = fmaf(silu_f(acc2[ei][hh]), w3r[hh], msum);
            #pragma unroll
            for (int m = 8; m >= 1; m >>= 1) msum += __shfl_xor(msum, m, 64);
            if (hg == 0){
                int ee = e0 + half*32 + e2 + ei;
                if (ee < E){
                    float mval = msum + b3;
                    float cwv = RCW[(size_t)ee*4 + 3];
                    int p = pe[(size_t)ee*2 + 1];
                    atomicAdd(&rho[p], mval * cwv);
                }
            }
        }
    }
}

extern "C" void kernel_launch(void* const* d_in, const int* in_sizes, int n_in,
                              void* d_out, int out_size, void* d_ws, size_t ws_size,
                              hipStream_t stream)
{
    const float* s_stack   = (const float*)d_in[0];
    const float* v_stack   = (const float*)d_in[1];
    const float* atom_xyz  = (const float*)d_in[2];
    const float* probe_xyz = (const float*)d_in[3];
    const float* cell      = (const float*)d_in[4];
    const float* disp      = (const float*)d_in[5];
    const float* attn_w1   = (const float*)d_in[6];
    const float* attn_b1   = (const float*)d_in[7];
    const float* attn_w2   = (const float*)d_in[8];
    const float* attn_b2   = (const float*)d_in[9];
    const float* msg_w1    = (const float*)d_in[10];
    const float* msg_b1    = (const float*)d_in[11];
    const float* msg_w2    = (const float*)d_in[12];
    const float* msg_b2    = (const float*)d_in[13];
    const float* msg_w3    = (const float*)d_in[14];
    const float* msg_b3    = (const float*)d_in[15];
    const int*   pe        = (const int*)d_in[16];

    const int N = in_sizes[0] / (L_DIM * F_DIM);
    const int E = in_sizes[16] / 2;
    const int P = out_size;

    float* ws = (float*)d_ws;
    // region 1: VJK | SJK | NI  (size N*1280 floats); EPI|RCW alias it after kA2
    float* VJK = ws;
    float* SJK = ws + (size_t)N * 3 * F_DIM;
    float* NI  = ws + (size_t)N * 4 * F_DIM;
    float* EPI = ws;                                   // aliases VJK region (after kA2)
    float* RCW = ws + (size_t)E * DRBF;
    // region 2: U | T
    float* Ubuf = ws + (size_t)N * 5 * F_DIM;
    float* Tbuf = ws + (size_t)N * 8 * F_DIM;

    hipMemsetAsync(d_out, 0, (size_t)P * sizeof(float), stream);

    const int gA = (N + 7) / 8;
    kA1<<<gA, 256, 0, stream>>>(s_stack, v_stack, attn_w1, attn_b1, attn_w2, attn_b2,
                                VJK, SJK, NI, N);
    kA2<<<gA, 256, 0, stream>>>(msg_w1, msg_b1, VJK, SJK, NI, Ubuf, Tbuf, N);

    const int gB0 = (E + 255) / 256;
    kB0<<<gB0, 256, 0, stream>>>(pe, disp, cell, atom_xyz, probe_xyz, EPI, RCW, E);

    const int gB1 = (E + 63) / 64;
    kB1<<<gB1, 256, 0, stream>>>(pe, EPI, RCW, Ubuf, Tbuf, msg_w1,
                                 msg_w2, msg_b2, msg_w3, msg_b3, (float*)d_out, E);
}